// Round 3
// baseline (1088.418 us; speedup 1.0000x reference)
//
#include <hip/hip_runtime.h>
#include <hip/hip_bf16.h>

#define L_SZ 1024
#define P_SZ 2048
#define HID 256
#define NH 8
#define HD 32
#define NRBF 50
#define CH 64
#define NCH 32

typedef unsigned int uint32;
typedef _Float16 half2_t __attribute__((ext_vector_type(2)));

__constant__ float kINV_SCALE = 0.17677669529663687f; // 1/sqrt(32)

static __device__ __forceinline__ unsigned short f2h(float f) {
    union { _Float16 h; unsigned short u; } x; x.h = (_Float16)f; return x.u;
}
static __device__ __forceinline__ float h2f(unsigned short u) {
    union { unsigned short u; _Float16 h; } x; x.u = u; return (float)x.h;
}
static __device__ __forceinline__ half2_t u2h2(uint32 u) {
    union { uint32 u; half2_t h; } x; x.u = u; return x.h;
}

// ---------------------------------------------------------------------------
// Kernel 1: Q = lig@Wq+bq (f32), K = prot@Wk+bk (f16), V = prot@Wv+bv (f16)
// ---------------------------------------------------------------------------
__global__ __launch_bounds__(64) void k_proj(
    const float* __restrict__ lig, const float* __restrict__ prot,
    const float* __restrict__ Wq, const float* __restrict__ bq,
    const float* __restrict__ Wk, const float* __restrict__ bk,
    const float* __restrict__ Wv, const float* __restrict__ bv,
    float* __restrict__ Qf, unsigned short* __restrict__ Kb,
    unsigned short* __restrict__ Vb)
{
    __shared__ float As[8 * HID];
    const int t = threadIdx.x;
    const int r0 = blockIdx.x * 8;

    const float* src; const float* W; const float* bias; int mode; int row0;
    if (r0 < L_SZ)            { src = lig  + (size_t)r0 * HID;               W = Wq; bias = bq; mode = 0; row0 = r0; }
    else if (r0 < L_SZ + P_SZ){ src = prot + (size_t)(r0 - L_SZ) * HID;      W = Wk; bias = bk; mode = 1; row0 = r0 - L_SZ; }
    else                      { src = prot + (size_t)(r0 - L_SZ - P_SZ)*HID; W = Wv; bias = bv; mode = 2; row0 = r0 - L_SZ - P_SZ; }

    float4* A4 = (float4*)As;
    const float4* S4 = (const float4*)src;
    #pragma unroll
    for (int j = 0; j < 8; ++j) A4[t + j * 64] = S4[t + j * 64];
    __syncthreads();

    float acc[8][4];
    #pragma unroll
    for (int r = 0; r < 8; ++r)
        #pragma unroll
        for (int c = 0; c < 4; ++c) acc[r][c] = 0.f;

    for (int k4 = 0; k4 < 64; ++k4) {
        float4 av[8];
        #pragma unroll
        for (int r = 0; r < 8; ++r) av[r] = A4[r * 64 + k4];
        #pragma unroll
        for (int kk = 0; kk < 4; ++kk) {
            const float* wr = W + (size_t)(k4 * 4 + kk) * HID + t;
            #pragma unroll
            for (int c = 0; c < 4; ++c) {
                float wv = wr[c * 64];
                #pragma unroll
                for (int r = 0; r < 8; ++r)
                    acc[r][c] += ((const float*)&av[r])[kk] * wv;
            }
        }
    }

    #pragma unroll
    for (int c = 0; c < 4; ++c) {
        const int col = t + c * 64;
        const float bb = bias[col];
        #pragma unroll
        for (int r = 0; r < 8; ++r) {
            float v = acc[r][c] + bb;
            size_t idx = (size_t)(row0 + r) * HID + col;
            if (mode == 0)      Qf[idx] = v;
            else if (mode == 1) Kb[idx] = f2h(v);
            else                Vb[idx] = f2h(v);
        }
    }
}

// ---------------------------------------------------------------------------
// Kernel 2: chunked/staged bias + QK^T + softmax + weights + PV.
// One block per ligand row. 256 threads, 2 blocks/CU (launch_bounds (256,2)).
// LDS: rbf chunk [0,12800) | K/V chunk (swizzled) [12800,45568)
//      | logits/weights f16 [45568,78336) | red [78336,78400)
// ---------------------------------------------------------------------------
__global__ __launch_bounds__(256, 2) void k_attn(
    const float* __restrict__ rbf, const float* __restrict__ Qf,
    const unsigned short* __restrict__ Kb, const unsigned short* __restrict__ Vb,
    const float* __restrict__ Wrbf, const float* __restrict__ brbf,
    float* __restrict__ attn_out, float* __restrict__ att_ws)
{
    __shared__ float4 smem4[4901];                       // 78416 B
    char* sm = (char*)smem4;
    float* rbfS = (float*)sm;                            // 64 rows x 50 f32
    char*  kvS  = sm + 12800;                            // 64 rows x 512 B (swizzled)
    unsigned short* slg = (unsigned short*)(sm + 45568); // [2048][8] f16
    float* red  = (float*)(sm + 78336);                  // [8]{m, 1/sum}

    const int l = blockIdx.x;
    const int t = threadIdx.x;
    const int r = t & 63;
    const int wv = t >> 6;
    const int h0 = __builtin_amdgcn_readfirstlane(2 * (t >> 6));
    const int h1 = h0 + 1;

    // ---- Q for this wave's 2 heads: 64 f32 -> 32 packed f16x2 regs ----
    half2_t qp[32];
    {
        const float4* qsrc = (const float4*)(Qf + (size_t)l * HID + h0 * HD);
        #pragma unroll
        for (int n = 0; n < 16; ++n) {
            float4 v = qsrc[n];
            half2_t a, b;
            a.x = (_Float16)v.x; a.y = (_Float16)v.y;
            b.x = (_Float16)v.z; b.y = (_Float16)v.w;
            qp[2 * n] = a; qp[2 * n + 1] = b;
        }
    }
    const float bh0 = brbf[h0], bh1 = brbf[h1];

    float mx0 = -3.0e38f, mx1 = -3.0e38f;

    // ================= Pass 1: logits (bias + QK) + running max ============
    float4 kst[8];
    float4 rst[4];
    {
        const float4* kg = (const float4*)Kb;
        #pragma unroll
        for (int n = 0; n < 8; ++n) kst[n] = kg[t + n * 256];
        const float4* rg = (const float4*)((const char*)rbf + (size_t)l * 409600);
        #pragma unroll
        for (int n = 0; n < 4; ++n) { int f = t + n * 256; if (f < 800) rst[n] = rg[f]; }
    }

    for (int c = 0; c < NCH; ++c) {
        // stage current chunk (K swizzled, rbf linear)
        #pragma unroll
        for (int n = 0; n < 8; ++n) {
            int fb = (t + n * 256) * 16;
            int sw = fb ^ (((fb >> 9) & 31) << 4);
            *(float4*)(kvS + sw) = kst[n];
        }
        #pragma unroll
        for (int n = 0; n < 4; ++n) { int f = t + n * 256; if (f < 800) ((float4*)rbfS)[f] = rst[n]; }
        __syncthreads();
        // prefetch next chunk (overlaps consume)
        if (c + 1 < NCH) {
            const float4* kg = (const float4*)(Kb + (size_t)(c + 1) * CH * HID);
            #pragma unroll
            for (int n = 0; n < 8; ++n) kst[n] = kg[t + n * 256];
            const float4* rg = (const float4*)((const char*)rbf + (size_t)l * 409600 + (size_t)(c + 1) * 12800);
            #pragma unroll
            for (int n = 0; n < 4; ++n) { int f = t + n * 256; if (f < 800) rst[n] = rg[f]; }
        }
        // ---- bias: rbf row r  dot  Wrbf[:,h0/h1] ----
        float s0 = bh0, s1 = bh1;
        const float2* rp = (const float2*)(rbfS + r * NRBF);
        #pragma unroll
        for (int j = 0; j < 25; ++j) {
            float2 v = rp[j];
            const float* wr = Wrbf + 2 * j * NH;
            s0 += v.x * wr[h0] + v.y * wr[NH + h0];
            s1 += v.x * wr[h1] + v.y * wr[NH + h1];
        }
        // ---- QK via v_dot2_f32_f16: K row r, bytes [wv*128, wv*128+128) ----
        float qk0 = 0.f, qk1 = 0.f;
        #pragma unroll
        for (int jw = 0; jw < 8; ++jw) {
            int inner = (wv * 128 + jw * 16) ^ ((r & 31) << 4);
            uint4 kb4 = *(const uint4*)(kvS + (r << 9) + inner);
            float* dst = (jw < 4) ? &qk0 : &qk1;
            *dst = __builtin_amdgcn_fdot2(u2h2(kb4.x), qp[jw * 4 + 0], *dst, false);
            *dst = __builtin_amdgcn_fdot2(u2h2(kb4.y), qp[jw * 4 + 1], *dst, false);
            *dst = __builtin_amdgcn_fdot2(u2h2(kb4.z), qp[jw * 4 + 2], *dst, false);
            *dst = __builtin_amdgcn_fdot2(u2h2(kb4.w), qp[jw * 4 + 3], *dst, false);
        }
        float lg0 = qk0 * kINV_SCALE + s0;
        float lg1 = qk1 * kINV_SCALE + s1;
        mx0 = fmaxf(mx0, lg0); mx1 = fmaxf(mx1, lg1);
        uint32 pk = (uint32)f2h(lg0) | ((uint32)f2h(lg1) << 16);
        *(uint32*)((char*)slg + (size_t)(c * CH + r) * 16 + wv * 4) = pk;
        __syncthreads();
    }

    // ---- wave-local max ----
    #pragma unroll
    for (int msk = 1; msk < 64; msk <<= 1) {
        mx0 = fmaxf(mx0, __shfl_xor(mx0, msk));
        mx1 = fmaxf(mx1, __shfl_xor(mx1, msk));
    }
    // ---- sum pass (reads own slg entries) ----
    float sm0 = 0.f, sm1 = 0.f;
    for (int c = 0; c < NCH; ++c) {
        uint32 pk = *(const uint32*)((char*)slg + (size_t)(c * CH + r) * 16 + wv * 4);
        sm0 += __expf(h2f((unsigned short)(pk & 0xffffu)) - mx0);
        sm1 += __expf(h2f((unsigned short)(pk >> 16)) - mx1);
    }
    #pragma unroll
    for (int msk = 1; msk < 64; msk <<= 1) { sm0 += __shfl_xor(sm0, msk); sm1 += __shfl_xor(sm1, msk); }
    if (r == 0) {
        red[h0 * 2] = mx0; red[h0 * 2 + 1] = 1.f / sm0;
        red[h1 * 2] = mx1; red[h1 * 2 + 1] = 1.f / sm1;
    }
    __syncthreads();

    // ================= Pass 2: normalized weights (dense write) ============
    {
        const int hh = (t & 1) * 4;
        float m0 = red[hh * 2],     is0 = red[hh * 2 + 1];
        float m1 = red[hh * 2 + 2], is1 = red[hh * 2 + 3];
        float m2 = red[hh * 2 + 4], is2 = red[hh * 2 + 5];
        float m3 = red[hh * 2 + 6], is3 = red[hh * 2 + 7];
        float4* ao = (float4*)(attn_out + (size_t)l * P_SZ * NH);
        #pragma unroll
        for (int n = 0; n < 16; ++n) {
            int f = t + n * 256;
            int p = f >> 1;
            uint2 pk = *(const uint2*)((char*)slg + (size_t)p * 16 + hh * 2);
            float w0 = __expf(h2f((unsigned short)(pk.x & 0xffffu)) - m0) * is0;
            float w1 = __expf(h2f((unsigned short)(pk.x >> 16))    - m1) * is1;
            float w2 = __expf(h2f((unsigned short)(pk.y & 0xffffu)) - m2) * is2;
            float w3 = __expf(h2f((unsigned short)(pk.y >> 16))    - m3) * is3;
            ao[f] = make_float4(w0, w1, w2, w3);
            uint2 wb;
            wb.x = (uint32)f2h(w0) | ((uint32)f2h(w1) << 16);
            wb.y = (uint32)f2h(w2) | ((uint32)f2h(w3) << 16);
            *(uint2*)((char*)slg + (size_t)p * 16 + hh * 2) = wb;
        }
    }
    __syncthreads();

    // ================= Pass 3: PV with staged V ============================
    {
        const int hv = t >> 5;        // head 0..7
        const int dq = (t >> 3) & 3;  // dim quad
        const int ps = t & 7;         // p slice
        float acc[8] = {0.f,0.f,0.f,0.f,0.f,0.f,0.f,0.f};
        float4 vst[8];
        {
            const float4* vg = (const float4*)Vb;
            #pragma unroll
            for (int n = 0; n < 8; ++n) vst[n] = vg[t + n * 256];
        }
        for (int c = 0; c < NCH; ++c) {
            #pragma unroll
            for (int n = 0; n < 8; ++n) {
                int fb = (t + n * 256) * 16;
                int sw = fb ^ (((fb >> 9) & 31) << 4);
                *(float4*)(kvS + sw) = vst[n];
            }
            __syncthreads();
            if (c + 1 < NCH) {
                const float4* vg = (const float4*)(Vb + (size_t)(c + 1) * CH * HID);
                #pragma unroll
                for (int n = 0; n < 8; ++n) vst[n] = vg[t + n * 256];
            }
            #pragma unroll
            for (int m = 0; m < 8; ++m) {
                int rr = m * 8 + ps;   // m-major: slg reads spread over 8 banks
                int p = c * CH + rr;
                float w = h2f(slg[p * NH + hv]);
                int inner = (hv * 64 + dq * 16) ^ ((rr & 31) << 4);
                uint4 vb4 = *(const uint4*)(kvS + (rr << 9) + inner);
                half2_t h;
                h = u2h2(vb4.x); acc[0] += w * (float)h.x; acc[1] += w * (float)h.y;
                h = u2h2(vb4.y); acc[2] += w * (float)h.x; acc[3] += w * (float)h.y;
                h = u2h2(vb4.z); acc[4] += w * (float)h.x; acc[5] += w * (float)h.y;
                h = u2h2(vb4.w); acc[6] += w * (float)h.x; acc[7] += w * (float)h.y;
            }
            __syncthreads();
        }
        #pragma unroll
        for (int d = 0; d < 8; ++d) {
            acc[d] += __shfl_xor(acc[d], 1);
            acc[d] += __shfl_xor(acc[d], 2);
            acc[d] += __shfl_xor(acc[d], 4);
        }
        if (ps == 0) {
            float* dst = att_ws + (size_t)l * HID + hv * HD + dq * 8;
            *(float4*)dst       = make_float4(acc[0], acc[1], acc[2], acc[3]);
            *(float4*)(dst + 4) = make_float4(acc[4], acc[5], acc[6], acc[7]);
        }
    }
}

// ---------------------------------------------------------------------------
// Kernel 3: y = lig + attended@Wo + bo; LayerNorm
// ---------------------------------------------------------------------------
__global__ __launch_bounds__(256) void k_out(
    const float* __restrict__ att, const float* __restrict__ lig,
    const float* __restrict__ Wo, const float* __restrict__ bo,
    const float* __restrict__ gamma, const float* __restrict__ beta,
    float* __restrict__ out)
{
    __shared__ float a[HID];
    __shared__ float red[8];
    const int l = blockIdx.x, t = threadIdx.x;
    if (t < 64) ((float4*)a)[t] = ((const float4*)(att + (size_t)l * HID))[t];
    __syncthreads();

    float acc = bo[t];
    for (int k4 = 0; k4 < 64; ++k4) {
        float4 av = ((float4*)a)[k4];
        const float* wr = Wo + (size_t)(k4 * 4) * HID + t;
        acc += av.x * wr[0];
        acc += av.y * wr[HID];
        acc += av.z * wr[2 * HID];
        acc += av.w * wr[3 * HID];
    }
    float y = lig[(size_t)l * HID + t] + acc;

    float s = y, sq = y * y;
    #pragma unroll
    for (int msk = 1; msk < 64; msk <<= 1) {
        s  += __shfl_xor(s, msk);
        sq += __shfl_xor(sq, msk);
    }
    const int lane = t & 63, wvi = t >> 6;
    if (lane == 0) { red[wvi * 2] = s; red[wvi * 2 + 1] = sq; }
    __syncthreads();
    float ts = red[0] + red[2] + red[4] + red[6];
    float tq = red[1] + red[3] + red[5] + red[7];
    float mu = ts * (1.0f / HID);
    float var = tq * (1.0f / HID) - mu * mu;
    out[(size_t)l * HID + t] = (y - mu) * rsqrtf(var + 1e-5f) * gamma[t] + beta[t];
}

// ---------------------------------------------------------------------------
extern "C" void kernel_launch(void* const* d_in, const int* in_sizes, int n_in,
                              void* d_out, int out_size, void* d_ws, size_t ws_size,
                              hipStream_t stream)
{
    (void)in_sizes; (void)n_in; (void)out_size; (void)ws_size;

    const float* lig   = (const float*)d_in[0];
    const float* prot  = (const float*)d_in[1];
    const float* rbf   = (const float*)d_in[2];
    const float* Wq    = (const float*)d_in[5];
    const float* bq    = (const float*)d_in[6];
    const float* Wk    = (const float*)d_in[7];
    const float* bk    = (const float*)d_in[8];
    const float* Wv    = (const float*)d_in[9];
    const float* bv    = (const float*)d_in[10];
    const float* Wrbf  = (const float*)d_in[11];
    const float* brbf  = (const float*)d_in[12];
    const float* Wo    = (const float*)d_in[13];
    const float* bo    = (const float*)d_in[14];
    const float* gamma = (const float*)d_in[15];
    const float* beta  = (const float*)d_in[16];

    float* out0 = (float*)d_out;                          // [1024,256]
    float* attn = (float*)d_out + (size_t)L_SZ * HID;     // [1024,2048,8]

    char* ws = (char*)d_ws;
    float*          Qf     = (float*)ws;                          // 1 MB
    unsigned short* Kb     = (unsigned short*)(ws + (1u << 20));  // 1 MB
    unsigned short* Vb     = (unsigned short*)(ws + (2u << 20));  // 1 MB
    float*          att_ws = (float*)(ws + (3u << 20));           // 1 MB

    hipLaunchKernelGGL(k_proj, dim3((L_SZ + 2 * P_SZ) / 8), dim3(64), 0, stream,
                       lig, prot, Wq, bq, Wk, bk, Wv, bv, Qf, Kb, Vb);
    hipLaunchKernelGGL(k_attn, dim3(L_SZ), dim3(256), 0, stream,
                       rbf, Qf, Kb, Vb, Wrbf, brbf, attn, att_ws);
    hipLaunchKernelGGL(k_out, dim3(L_SZ), dim3(256), 0, stream,
                       att_ws, lig, Wo, bo, gamma, beta, out0);
}

// Round 5
// 314.379 us; speedup vs baseline: 3.4621x; 3.4621x over previous
//
#include <hip/hip_runtime.h>
#include <hip/hip_bf16.h>

#define L_SZ 1024
#define P_SZ 2048
#define HID 256
#define NH 8
#define HD 32
#define NRBF 50
#define CH 32
#define NCH 64

typedef unsigned int uint32;
typedef _Float16 half2_t __attribute__((ext_vector_type(2)));
typedef __fp16 fp16x2_t __attribute__((ext_vector_type(2)));

__constant__ float kINV_SCALE = 0.17677669529663687f; // 1/sqrt(32)

static __device__ __forceinline__ unsigned short f2h(float f) {
    union { _Float16 h; unsigned short u; } x; x.h = (_Float16)f; return x.u;
}
static __device__ __forceinline__ float h2f(unsigned short u) {
    union { unsigned short u; _Float16 h; } x; x.u = u; return (float)x.h;
}
static __device__ __forceinline__ half2_t u2h2(uint32 u) {
    union { uint32 u; half2_t h; } x; x.u = u; return x.h;
}
static __device__ __forceinline__ half2_t pk2h(float a, float b) {
    union { fp16x2_t p; half2_t h; } x; x.p = __builtin_amdgcn_cvt_pkrtz(a, b); return x.h;
}

// async global->LDS, 16B per lane. LDS dest = uniform base + lane*16.
static __device__ __forceinline__ void g2l16(const void* g, void* l) {
    __builtin_amdgcn_global_load_lds(
        (__attribute__((address_space(1))) void*)(void*)g,
        (__attribute__((address_space(3))) void*)l, 16, 0, 0);
}
static __device__ __forceinline__ void g2l4(const void* g, void* l) {
    __builtin_amdgcn_global_load_lds(
        (__attribute__((address_space(1))) void*)(void*)g,
        (__attribute__((address_space(3))) void*)l, 4, 0, 0);
}

// ---------------------------------------------------------------------------
// Kernel 1: Q = lig@Wq+bq (f32), K = prot@Wk+bk (f16), V = prot@Wv+bv (f16)
// ---------------------------------------------------------------------------
__global__ __launch_bounds__(64) void k_proj(
    const float* __restrict__ lig, const float* __restrict__ prot,
    const float* __restrict__ Wq, const float* __restrict__ bq,
    const float* __restrict__ Wk, const float* __restrict__ bk,
    const float* __restrict__ Wv, const float* __restrict__ bv,
    float* __restrict__ Qf, unsigned short* __restrict__ Kb,
    unsigned short* __restrict__ Vb)
{
    __shared__ float As[8 * HID];
    const int t = threadIdx.x;
    const int r0 = blockIdx.x * 8;

    const float* src; const float* W; const float* bias; int mode; int row0;
    if (r0 < L_SZ)            { src = lig  + (size_t)r0 * HID;               W = Wq; bias = bq; mode = 0; row0 = r0; }
    else if (r0 < L_SZ + P_SZ){ src = prot + (size_t)(r0 - L_SZ) * HID;      W = Wk; bias = bk; mode = 1; row0 = r0 - L_SZ; }
    else                      { src = prot + (size_t)(r0 - L_SZ - P_SZ)*HID; W = Wv; bias = bv; mode = 2; row0 = r0 - L_SZ - P_SZ; }

    float4* A4 = (float4*)As;
    const float4* S4 = (const float4*)src;
    #pragma unroll
    for (int j = 0; j < 8; ++j) A4[t + j * 64] = S4[t + j * 64];
    __syncthreads();

    float acc[8][4];
    #pragma unroll
    for (int r = 0; r < 8; ++r)
        #pragma unroll
        for (int c = 0; c < 4; ++c) acc[r][c] = 0.f;

    for (int k4 = 0; k4 < 64; ++k4) {
        float4 av[8];
        #pragma unroll
        for (int r = 0; r < 8; ++r) av[r] = A4[r * 64 + k4];
        #pragma unroll
        for (int kk = 0; kk < 4; ++kk) {
            const float* wr = W + (size_t)(k4 * 4 + kk) * HID + t;
            #pragma unroll
            for (int c = 0; c < 4; ++c) {
                float wv = wr[c * 64];
                #pragma unroll
                for (int r = 0; r < 8; ++r)
                    acc[r][c] += ((const float*)&av[r])[kk] * wv;
            }
        }
    }

    #pragma unroll
    for (int c = 0; c < 4; ++c) {
        const int col = t + c * 64;
        const float bb = bias[col];
        #pragma unroll
        for (int r = 0; r < 8; ++r) {
            float v = acc[r][c] + bb;
            size_t idx = (size_t)(row0 + r) * HID + col;
            if (mode == 0)      Qf[idx] = v;
            else if (mode == 1) Kb[idx] = f2h(v);
            else                Vb[idx] = f2h(v);
        }
    }
}

// ---------------------------------------------------------------------------
// Kernel 2: fused bias + QK^T + softmax + weights + PV.
// One block per ligand row, 256 threads, 2 blocks/CU.
// All staging via async global_load_lds into double-buffered LDS; zero
// persistent staging registers (round-3 scratch spill fix).
// LDS: kv dbuf 2x16384 | rbf dbuf 2x6400 @32768 | slg f16 [2048][8] @45568
//      (dword-XOR swizzled) | red[16] @78336. Total 78400 B.
// ---------------------------------------------------------------------------
__global__ __launch_bounds__(256, 2) void k_attn(
    const float* __restrict__ rbf, const float* __restrict__ Qf,
    const unsigned short* __restrict__ Kb, const unsigned short* __restrict__ Vb,
    const float* __restrict__ Wrbf, const float* __restrict__ brbf,
    float* __restrict__ attn_out, float* __restrict__ att_ws)
{
    __shared__ __align__(16) char sm[78400];
    char* slgB = sm + 45568;
    float* red = (float*)(sm + 78336);

    const int t = threadIdx.x;
    const int lane = t & 63;
    const int wv = t >> 6;
    const int r = t & 31;     // protein row within chunk
    const int h = t >> 5;     // head 0..7
    const int l = blockIdx.x;

    // stage one 32-row K or V chunk (16 KB), XOR-swizzled via pre-swizzled
    // global source (LDS dest stays linear per global_load_lds semantics)
    auto stageKV = [&](const unsigned short* src, int c, char* dst) {
        const char* gb = (const char*)src + (size_t)c * (CH * 512);
        #pragma unroll
        for (int k = 0; k < 4; ++k) {
            int s = wv * 4 + k;               // 1KB slab 0..15
            int row = s * 2 + (lane >> 5);
            int off = ((lane & 31) ^ (row & 31)) << 4;
            g2l16(gb + row * 512 + off, dst + s * 1024);
        }
    };
    // stage one 32-row rbf chunk (6400 B), linear
    auto stageRBF = [&](int c, char* dst) {
        const char* gb = (const char*)rbf + (size_t)l * 409600 + (size_t)c * 6400;
        g2l16(gb + wv * 1024 + (lane << 4), dst + wv * 1024);
        if (wv == 0)      g2l16(gb + 4096 + (lane << 4), dst + 4096);
        else if (wv == 1) g2l16(gb + 5120 + (lane << 4), dst + 5120);
        else if (wv == 2) g2l4 (gb + 6144 + (lane << 2), dst + 6144);
    };

    // ---- per-thread preloads: Wrbf column h (25 half2), Q head h (16 half2)
    half2_t wrb[25];
    #pragma unroll
    for (int j = 0; j < 25; ++j)
        wrb[j] = pk2h(Wrbf[(2 * j) * NH + h], Wrbf[(2 * j + 1) * NH + h]);
    const float bh = brbf[h];

    half2_t qp[16];
    {
        const float* qq = Qf + (size_t)l * HID + h * HD;
        #pragma unroll
        for (int n = 0; n < 16; ++n)
            qp[n] = pk2h(qq[2 * n], qq[2 * n + 1]);
    }

    // slg address swizzle: dword d of row p stored at d ^ ((p>>3)&3).
    const int doff = ((((h >> 1) ^ ((r >> 3) & 3)) << 2) | ((h & 1) << 1));

    // ================= Pass 1: logits + running max =========================
    stageKV(Kb, 0, sm);
    stageRBF(0, sm + 32768);
    asm volatile("s_waitcnt vmcnt(0)" ::: "memory");
    __syncthreads();

    float mx = -3.0e38f;
    for (int c = 0; c < NCH; ++c) {
        const int cb = c & 1;
        char* kb = sm + cb * 16384;
        char* rb = sm + 32768 + cb * 6400;
        if (c + 1 < NCH) {                       // async prefetch next chunk
            stageKV(Kb, c + 1, sm + (cb ^ 1) * 16384);
            stageRBF(c + 1, sm + 32768 + (cb ^ 1) * 6400);
        }
        // bias = brbf[h] + rbf[l, p, :] . Wrbf[:, h]
        float bias = bh;
        const char* rrow = rb + r * 200;
        #pragma unroll
        for (int j = 0; j < 25; ++j) {
            float2 v = *(const float2*)(rrow + j * 8);
            bias = __builtin_amdgcn_fdot2(pk2h(v.x, v.y), wrb[j], bias, false);
        }
        // qk = Q[l,h,:] . K[p,h,:]
        float qk = 0.f;
        const char* krow = kb + r * 512;
        #pragma unroll
        for (int jw = 0; jw < 4; ++jw) {
            int off = (h * 64 + jw * 16) ^ (r << 4);
            uint4 kk = *(const uint4*)(krow + off);
            qk = __builtin_amdgcn_fdot2(u2h2(kk.x), qp[jw * 4 + 0], qk, false);
            qk = __builtin_amdgcn_fdot2(u2h2(kk.y), qp[jw * 4 + 1], qk, false);
            qk = __builtin_amdgcn_fdot2(u2h2(kk.z), qp[jw * 4 + 2], qk, false);
            qk = __builtin_amdgcn_fdot2(u2h2(kk.w), qp[jw * 4 + 3], qk, false);
        }
        float lg = qk * kINV_SCALE + bias;
        mx = fmaxf(mx, lg);
        *(unsigned short*)(slgB + (size_t)((c * CH + r) * 16) + doff) = f2h(lg);

        asm volatile("s_waitcnt vmcnt(0)" ::: "memory");
        __syncthreads();
    }

    // ---- softmax stats: half-wave butterflies (32 lanes own head h) ----
    #pragma unroll
    for (int msk = 1; msk <= 16; msk <<= 1) mx = fmaxf(mx, __shfl_xor(mx, msk));
    float sme = 0.f;
    for (int c = 0; c < NCH; ++c) {
        unsigned short u = *(const unsigned short*)(slgB + (size_t)((c * CH + r) * 16) + doff);
        sme += __expf(h2f(u) - mx);
    }
    #pragma unroll
    for (int msk = 1; msk <= 16; msk <<= 1) sme += __shfl_xor(sme, msk);
    if ((t & 31) == 0) { red[h * 2] = mx; red[h * 2 + 1] = 1.f / sme; }

    stageKV(Vb, 0, sm);          // overlap V chunk-0 stage with pass 2
    __syncthreads();

    // ================= Pass 2: normalized weights ===========================
    {
        float mh[8], ih[8];
        #pragma unroll
        for (int hh = 0; hh < 8; ++hh) { mh[hh] = red[hh * 2]; ih[hh] = red[hh * 2 + 1]; }
        const int sel = t & 1;                       // 0: heads 0-3, 1: heads 4-7
        float m0 = sel ? mh[4] : mh[0], i0 = sel ? ih[4] : ih[0];
        float m1 = sel ? mh[5] : mh[1], i1 = sel ? ih[5] : ih[1];
        float m2 = sel ? mh[6] : mh[2], i2 = sel ? ih[6] : ih[2];
        float m3 = sel ? mh[7] : mh[3], i3 = sel ? ih[7] : ih[3];
        const int x = (t >> 4) & 3;                  // (p>>3)&3, const per thread
        const int dA = (((2 * sel)     ^ x) << 2);
        const int dB = (((2 * sel + 1) ^ x) << 2);
        float4* ao = (float4*)(attn_out + (size_t)l * (P_SZ * NH));
        #pragma unroll
        for (int n = 0; n < 16; ++n) {
            int f = t + n * 256;
            int p = (t >> 1) + n * 128;
            char* rowp = slgB + p * 16;
            uint32 a = *(uint32*)(rowp + dA);
            uint32 b = *(uint32*)(rowp + dB);
            float w0 = __expf(h2f((unsigned short)(a & 0xffffu)) - m0) * i0;
            float w1 = __expf(h2f((unsigned short)(a >> 16))     - m1) * i1;
            float w2 = __expf(h2f((unsigned short)(b & 0xffffu)) - m2) * i2;
            float w3 = __expf(h2f((unsigned short)(b >> 16))     - m3) * i3;
            ao[f] = make_float4(w0, w1, w2, w3);
            *(uint32*)(rowp + dA) = (uint32)f2h(w0) | ((uint32)f2h(w1) << 16);
            *(uint32*)(rowp + dB) = (uint32)f2h(w2) | ((uint32)f2h(w3) << 16);
        }
    }
    asm volatile("s_waitcnt vmcnt(0)" ::: "memory");
    __syncthreads();

    // ================= Pass 3: PV with double-buffered V =====================
    {
        const int h3 = t >> 5;        // head
        const int dq = (t >> 3) & 3;  // dim quad (8 dims)
        const int ps = t & 7;         // p slice
        const int vinner = h3 * 64 + dq * 16;
        float acc[8] = {0.f, 0.f, 0.f, 0.f, 0.f, 0.f, 0.f, 0.f};
        for (int c = 0; c < NCH; ++c) {
            const int cb = c & 1;
            char* vb = sm + cb * 16384;
            if (c + 1 < NCH) stageKV(Vb, c + 1, sm + (cb ^ 1) * 16384);
            #pragma unroll
            for (int m = 0; m < 4; ++m) {
                int rr = m * 8 + ps;
                int p = c * CH + rr;
                int dw = (((h3 >> 1) ^ m) << 2) | ((h3 & 1) << 1);
                float w = h2f(*(const unsigned short*)(slgB + p * 16 + dw));
                int off = vinner ^ (rr << 4);
                uint4 vvv = *(const uint4*)(vb + rr * 512 + off);
                half2_t x0 = u2h2(vvv.x), x1 = u2h2(vvv.y), x2 = u2h2(vvv.z), x3 = u2h2(vvv.w);
                acc[0] += w * (float)x0.x; acc[1] += w * (float)x0.y;
                acc[2] += w * (float)x1.x; acc[3] += w * (float)x1.y;
                acc[4] += w * (float)x2.x; acc[5] += w * (float)x2.y;
                acc[6] += w * (float)x3.x; acc[7] += w * (float)x3.y;
            }
            asm volatile("s_waitcnt vmcnt(0)" ::: "memory");
            __syncthreads();
        }
        #pragma unroll
        for (int d = 0; d < 8; ++d) {
            acc[d] += __shfl_xor(acc[d], 1);
            acc[d] += __shfl_xor(acc[d], 2);
            acc[d] += __shfl_xor(acc[d], 4);
        }
        if (ps == 0) {
            float* dst = att_ws + (size_t)l * HID + h3 * HD + dq * 8;
            *(float4*)dst       = make_float4(acc[0], acc[1], acc[2], acc[3]);
            *(float4*)(dst + 4) = make_float4(acc[4], acc[5], acc[6], acc[7]);
        }
    }
}

// ---------------------------------------------------------------------------
// Kernel 3: y = lig + attended@Wo + bo; LayerNorm
// ---------------------------------------------------------------------------
__global__ __launch_bounds__(256) void k_out(
    const float* __restrict__ att, const float* __restrict__ lig,
    const float* __restrict__ Wo, const float* __restrict__ bo,
    const float* __restrict__ gamma, const float* __restrict__ beta,
    float* __restrict__ out)
{
    __shared__ float a[HID];
    __shared__ float red[8];
    const int l = blockIdx.x, t = threadIdx.x;
    if (t < 64) ((float4*)a)[t] = ((const float4*)(att + (size_t)l * HID))[t];
    __syncthreads();

    float acc = bo[t];
    for (int k4 = 0; k4 < 64; ++k4) {
        float4 av = ((float4*)a)[k4];
        const float* wr = Wo + (size_t)(k4 * 4) * HID + t;
        acc += av.x * wr[0];
        acc += av.y * wr[HID];
        acc += av.z * wr[2 * HID];
        acc += av.w * wr[3 * HID];
    }
    float y = lig[(size_t)l * HID + t] + acc;

    float s = y, sq = y * y;
    #pragma unroll
    for (int msk = 1; msk < 64; msk <<= 1) {
        s  += __shfl_xor(s, msk);
        sq += __shfl_xor(sq, msk);
    }
    const int lane = t & 63, wvi = t >> 6;
    if (lane == 0) { red[wvi * 2] = s; red[wvi * 2 + 1] = sq; }
    __syncthreads();
    float ts = red[0] + red[2] + red[4] + red[6];
    float tq = red[1] + red[3] + red[5] + red[7];
    float mu = ts * (1.0f / HID);
    float var = tq * (1.0f / HID) - mu * mu;
    out[(size_t)l * HID + t] = (y - mu) * rsqrtf(var + 1e-5f) * gamma[t] + beta[t];
}

// ---------------------------------------------------------------------------
extern "C" void kernel_launch(void* const* d_in, const int* in_sizes, int n_in,
                              void* d_out, int out_size, void* d_ws, size_t ws_size,
                              hipStream_t stream)
{
    (void)in_sizes; (void)n_in; (void)out_size; (void)ws_size;

    const float* lig   = (const float*)d_in[0];
    const float* prot  = (const float*)d_in[1];
    const float* rbf   = (const float*)d_in[2];
    const float* Wq    = (const float*)d_in[5];
    const float* bq    = (const float*)d_in[6];
    const float* Wk    = (const float*)d_in[7];
    const float* bk    = (const float*)d_in[8];
    const float* Wv    = (const float*)d_in[9];
    const float* bv    = (const float*)d_in[10];
    const float* Wrbf  = (const float*)d_in[11];
    const float* brbf  = (const float*)d_in[12];
    const float* Wo    = (const float*)d_in[13];
    const float* bo    = (const float*)d_in[14];
    const float* gamma = (const float*)d_in[15];
    const float* beta  = (const float*)d_in[16];

    float* out0 = (float*)d_out;                          // [1024,256]
    float* attn = (float*)d_out + (size_t)L_SZ * HID;     // [1024,2048,8]

    char* ws = (char*)d_ws;
    float*          Qf     = (float*)ws;                          // 1 MB
    unsigned short* Kb     = (unsigned short*)(ws + (1u << 20));  // 1 MB
    unsigned short* Vb     = (unsigned short*)(ws + (2u << 20));  // 1 MB
    float*          att_ws = (float*)(ws + (3u << 20));           // 1 MB

    hipLaunchKernelGGL(k_proj, dim3((L_SZ + 2 * P_SZ) / 8), dim3(64), 0, stream,
                       lig, prot, Wq, bq, Wk, bk, Wv, bv, Qf, Kb, Vb);
    hipLaunchKernelGGL(k_attn, dim3(L_SZ), dim3(256), 0, stream,
                       rbf, Qf, Kb, Vb, Wrbf, brbf, attn, att_ws);
    hipLaunchKernelGGL(k_out, dim3(L_SZ), dim3(256), 0, stream,
                       att_ws, lig, Wo, bo, gamma, beta, out0);
}